// Round 1
// baseline (854.432 us; speedup 1.0000x reference)
//
#include <hip/hip_runtime.h>

#define NPTS 50000
#define HN 32
#define INF1 128
#define OUTF3 256
#define MIDF 64
#define KP 15
#define EPSV 1e-6f
#define SLOPE 0.1f
// KP_EXTENT = 1.2 * 2.0 / 5.0
#define KPE 0.48f

// ---------------- generic row GEMM: C[n, c] = sum_i A[n,i] * W[i,c] ----------------
template<int INF, int OUTF, int PPB>
__global__ __launch_bounds__(256)
void k_rowgemm(const float* __restrict__ A, const float* __restrict__ W,
               float* __restrict__ C, int npts) {
    constexpr int G = 256 / OUTF;          // point groups per block
    int t  = threadIdx.x;
    int pg = t / OUTF;
    int c  = t % OUTF;
    long n0 = (long)blockIdx.x * (G * PPB) + (long)pg * PPB;

    float acc[PPB];
#pragma unroll
    for (int p = 0; p < PPB; p++) acc[p] = 0.f;

    long rows[PPB];
#pragma unroll
    for (int p = 0; p < PPB; p++) {
        long r = n0 + p;
        rows[p] = (r < npts) ? r : (long)(npts - 1);
    }

#pragma unroll 4
    for (int i = 0; i < INF; i++) {
        float w = W[i * OUTF + c];
#pragma unroll
        for (int p = 0; p < PPB; p++)
            acc[p] += A[rows[p] * INF + i] * w;
    }

#pragma unroll
    for (int p = 0; p < PPB; p++) {
        long r = n0 + p;
        if (r < npts) C[r * OUTF + c] = acc[p];
    }
}

// ---------------- column stats accumulation (coalesced, atomics) ----------------
__global__ __launch_bounds__(256)
void k_colstats_acc(const float* __restrict__ X, int total, int cmask,
                    float* __restrict__ acc, float* __restrict__ accsq) {
    int T  = blockIdx.x * 256 + threadIdx.x;
    int TT = gridDim.x * 256;
    float s = 0.f, sq = 0.f;
    for (int i = T; i < total; i += TT) {
        float v = X[i];
        s += v; sq += v * v;
    }
    __shared__ float ls[256], lq[256];
    int tid = threadIdx.x;
    ls[tid] = s; lq[tid] = sq;
    __syncthreads();
    int ncols = cmask + 1;
    for (int off = 128; off >= ncols; off >>= 1) {
        if (tid < off) { ls[tid] += ls[tid + off]; lq[tid] += lq[tid + off]; }
        __syncthreads();
    }
    if (tid < ncols) {
        atomicAdd(&acc[tid],   ls[tid]);
        atomicAdd(&accsq[tid], lq[tid]);
    }
}

// ---------------- finalize stats -> scale/shift ----------------
__global__ __launch_bounds__(256)
void k_finstats(const float* __restrict__ acc, const float* __restrict__ accsq,
                const float* __restrict__ g, const float* __restrict__ b,
                float* __restrict__ scale, float* __restrict__ shift,
                int ncols, float inv_n) {
    int c = threadIdx.x;
    if (c < ncols) {
        float m   = acc[c] * inv_n;
        float var = accsq[c] * inv_n - m * m;
        float sc  = g[c] * rsqrtf(var + EPSV);
        scale[c] = sc;
        shift[c] = b[c] - sc * m;
    }
}

// ---------------- BN + leaky relu apply (in place) ----------------
__global__ __launch_bounds__(256)
void k_bnlrelu(float* __restrict__ X, const float* __restrict__ sc,
               const float* __restrict__ sh, int cmask, int total) {
    int T  = blockIdx.x * 256 + threadIdx.x;
    int TT = gridDim.x * 256;
    for (int i = T; i < total; i += TT) {
        int c = i & cmask;
        float v = X[i] * sc[c] + sh[c];
        X[i] = (v >= 0.f) ? v : SLOPE * v;
    }
}

// ---------------- KPConv: 4 points per block (one per wave) ----------------
__global__ __launch_bounds__(256)
void k_kpconv(const float* __restrict__ qpts, const float* __restrict__ spts,
              const int* __restrict__ nbr, const float* __restrict__ x1,
              const float* __restrict__ kpp, const float* __restrict__ kwf,
              float* __restrict__ y) {
    __shared__ float infl[4][HN][16];   // [p][h][k], k padded to 16
    __shared__ float4 wfl[960];         // [kd] x {p0,p1,p2,p3}
    __shared__ float part[4][4][64];    // [wave][p][o]
    __shared__ int sidx[4][HN];

    int t  = threadIdx.x;
    int wq = t >> 6;
    int l  = t & 63;
    int n  = blockIdx.x * 4 + wq;

    // ---- phase 1: influences ----
    if (l < HN) {
        int idx = nbr[n * HN + l];
        sidx[wq][l] = idx;
        float qx = qpts[n * 3 + 0], qy = qpts[n * 3 + 1], qz = qpts[n * 3 + 2];
        float dx = spts[idx * 3 + 0] - qx;
        float dy = spts[idx * 3 + 1] - qy;
        float dz = spts[idx * 3 + 2] - qz;
#pragma unroll
        for (int k = 0; k < KP; k++) {
            float ex = dx - kpp[k * 3 + 0];
            float ey = dy - kpp[k * 3 + 1];
            float ez = dz - kpp[k * 3 + 2];
            float sq = ex * ex + ey * ey + ez * ez;
            float dist = sqrtf(fmaxf(sq, 1e-12f));
            infl[wq][l][k] = fmaxf(0.f, 1.f - dist * (1.f / KPE));
        }
    }
    __syncthreads();

    // ---- phase 2: wf[k][d] = sum_h infl[h][k] * x1[idx_h][d], lane = d ----
    float wfa[KP];
#pragma unroll
    for (int k = 0; k < KP; k++) wfa[k] = 0.f;

    for (int h = 0; h < HN; h++) {
        int idx = sidx[wq][h];
        float v = x1[(long)idx * MIDF + l];
        const float4* ip = (const float4*)(&infl[wq][h][0]);
        float4 i0 = ip[0], i1 = ip[1], i2 = ip[2], i3 = ip[3];
        wfa[0]  += i0.x * v;  wfa[1]  += i0.y * v;  wfa[2]  += i0.z * v;  wfa[3]  += i0.w * v;
        wfa[4]  += i1.x * v;  wfa[5]  += i1.y * v;  wfa[6]  += i1.z * v;  wfa[7]  += i1.w * v;
        wfa[8]  += i2.x * v;  wfa[9]  += i2.y * v;  wfa[10] += i2.z * v;  wfa[11] += i2.w * v;
        wfa[12] += i3.x * v;  wfa[13] += i3.y * v;  wfa[14] += i3.z * v;
    }
#pragma unroll
    for (int k = 0; k < KP; k++)
        ((float*)wfl)[(k * 64 + l) * 4 + wq] = wfa[k];
    __syncthreads();

    // ---- phase 3: y[p][o] = sum_kd wf[p][kd] * kw[kd][o]; waves split kd range ----
    float a0 = 0.f, a1 = 0.f, a2 = 0.f, a3 = 0.f;
    int kd0 = wq * 240;
    for (int j = 0; j < 240; j++) {
        int kd = kd0 + j;
        float w = kwf[kd * 64 + l];
        float4 wf4 = wfl[kd];
        a0 += wf4.x * w; a1 += wf4.y * w; a2 += wf4.z * w; a3 += wf4.w * w;
    }
    part[wq][0][l] = a0; part[wq][1][l] = a1; part[wq][2][l] = a2; part[wq][3][l] = a3;
    __syncthreads();

    int p = t >> 6;  // reuse wave id as point id
    float s = part[0][p][l] + part[1][p][l] + part[2][p][l] + part[3][p][l];
    y[(long)(blockIdx.x * 4 + p) * MIDF + l] = s;
}

// ---------------- final: lrelu(lrelu_bn(x3) + lrelu_bn(sc)) ----------------
__global__ __launch_bounds__(256)
void k_final(const float* __restrict__ x3, float* __restrict__ out,
             const float* __restrict__ s3, const float* __restrict__ h3,
             const float* __restrict__ sS, const float* __restrict__ hS,
             int total) {
    int T  = blockIdx.x * 256 + threadIdx.x;
    int TT = gridDim.x * 256;
    for (int i = T; i < total; i += TT) {
        int c = i & 255;
        float a = x3[i] * s3[c] + h3[c];
        a = (a >= 0.f) ? a : SLOPE * a;
        float b = out[i] * sS[c] + hS[c];
        b = (b >= 0.f) ? b : SLOPE * b;
        float v = a + b;
        out[i] = (v >= 0.f) ? v : SLOPE * v;
    }
}

extern "C" void kernel_launch(void* const* d_in, const int* in_sizes, int n_in,
                              void* d_out, int out_size, void* d_ws, size_t ws_size,
                              hipStream_t stream) {
    const float* qp   = (const float*)d_in[0];
    const float* sp   = (const float*)d_in[1];
    const int*   nbr  = (const int*)d_in[2];
    const float* feat = (const float*)d_in[3];
    const float* kpp  = (const float*)d_in[4];
    const float* w1   = (const float*)d_in[5];
    const float* g1   = (const float*)d_in[6];
    const float* b1   = (const float*)d_in[7];
    const float* kw   = (const float*)d_in[8];
    const float* g2   = (const float*)d_in[9];
    const float* b2   = (const float*)d_in[10];
    const float* w3   = (const float*)d_in[11];
    const float* g3   = (const float*)d_in[12];
    const float* b3   = (const float*)d_in[13];
    const float* wsw  = (const float*)d_in[14];
    const float* gs   = (const float*)d_in[15];
    const float* bs   = (const float*)d_in[16];
    float* out = (float*)d_out;

    float* w   = (float*)d_ws;
    float* x1  = w;                    // N*64
    float* x2  = w + 3200000;          // N*64
    float* x3  = w + 6400000;          // N*256
    float* st  = w + 19200000;         // stats region
    float* acc1 = st +    0, *q1 = st +   64;
    float* acc2 = st +  128, *q2 = st +  192;
    float* acc3 = st +  256, *q3 = st +  512;
    float* accS = st +  768, *qS = st + 1024;
    float* s1 = st + 1280, *h1 = st + 1344;
    float* s2 = st + 1408, *h2 = st + 1472;
    float* s3 = st + 1536, *h3 = st + 1792;
    float* sS = st + 2048, *hS = st + 2304;

    hipMemsetAsync(st, 0, 1280 * sizeof(float), stream);

    const float invN = 1.f / (float)NPTS;

    // conv1: x1 = lrelu(bn(feat @ w1))
    k_rowgemm<INF1, MIDF, 8><<<1563, 256, 0, stream>>>(feat, w1, x1, NPTS);
    k_colstats_acc<<<256, 256, 0, stream>>>(x1, NPTS * MIDF, 63, acc1, q1);
    k_finstats<<<1, 256, 0, stream>>>(acc1, q1, g1, b1, s1, h1, MIDF, invN);
    k_bnlrelu<<<2048, 256, 0, stream>>>(x1, s1, h1, 63, NPTS * MIDF);

    // conv2: KPConv + bn + lrelu
    k_kpconv<<<NPTS / 4, 256, 0, stream>>>(qp, sp, nbr, x1, kpp, kw, x2);
    k_colstats_acc<<<256, 256, 0, stream>>>(x2, NPTS * MIDF, 63, acc2, q2);
    k_finstats<<<1, 256, 0, stream>>>(acc2, q2, g2, b2, s2, h2, MIDF, invN);
    k_bnlrelu<<<2048, 256, 0, stream>>>(x2, s2, h2, 63, NPTS * MIDF);

    // conv3: x3 = x2 @ w3 (BN folded into final)
    k_rowgemm<MIDF, OUTF3, 8><<<6250, 256, 0, stream>>>(x2, w3, x3, NPTS);
    k_colstats_acc<<<256, 256, 0, stream>>>(x3, NPTS * OUTF3, 255, acc3, q3);
    k_finstats<<<1, 256, 0, stream>>>(acc3, q3, g3, b3, s3, h3, OUTF3, invN);

    // shortcut: sc = feat @ ws  (stored in d_out)
    k_rowgemm<INF1, OUTF3, 8><<<6250, 256, 0, stream>>>(feat, wsw, out, NPTS);
    k_colstats_acc<<<256, 256, 0, stream>>>(out, NPTS * OUTF3, 255, accS, qS);
    k_finstats<<<1, 256, 0, stream>>>(accS, qS, gs, bs, sS, hS, OUTF3, invN);

    // final combine
    k_final<<<4096, 256, 0, stream>>>(x3, out, s3, h3, sS, hS, NPTS * OUTF3);
}

// Round 2
// 446.729 us; speedup vs baseline: 1.9126x; 1.9126x over previous
//
#include <hip/hip_runtime.h>

#define NPTS 50000
#define HN 32
#define INF1 128
#define OUTF3 256
#define MIDF 64
#define KP 15
#define EPSV 1e-6f
#define SLOPE 0.1f
#define KPE 0.48f   // 1.2 * 2.0 / 5.0

typedef __attribute__((ext_vector_type(8))) short short8;   // 8 bf16
typedef __attribute__((ext_vector_type(4))) float float4v;  // MFMA acc

__device__ inline unsigned short f2bf(float f) {
    union { float f; unsigned u; } v; v.f = f;
    unsigned r = v.u + 0x7fff + ((v.u >> 16) & 1);
    return (unsigned short)(r >> 16);
}

// ---------- convert f32 -> bf16, 4 elems/thread ----------
__global__ __launch_bounds__(256)
void k_tobf(const float* __restrict__ X, unsigned short* __restrict__ Y, int total) {
    int i = (blockIdx.x * 256 + threadIdx.x) * 4;
    if (i >= total) return;
    float4 v = *(const float4*)(X + i);
    Y[i + 0] = f2bf(v.x); Y[i + 1] = f2bf(v.y);
    Y[i + 2] = f2bf(v.z); Y[i + 3] = f2bf(v.w);
}

// ---------- repack W[K][N] f32 -> B-fragment order bf16 ----------
// Wp[s][nt][lane][8]: lane wants B[k=s*32+(l>>4)*8+j][n=nt*16+(l&15)]
__global__ __launch_bounds__(256)
void k_repack(const float* __restrict__ W, unsigned short* __restrict__ Wp,
              int K, int N) {
    int id = blockIdx.x * 256 + threadIdx.x;
    int NT = N / 16;
    int total = (K / 32) * NT * 64;
    if (id >= total) return;
    int l  = id & 63;
    int nt = (id >> 6) % NT;
    int s  = id / (64 * NT);
    int n  = nt * 16 + (l & 15);
    int k0 = s * 32 + ((l >> 4) & 3) * 8;
#pragma unroll
    for (int j = 0; j < 8; j++)
        Wp[id * 8 + j] = f2bf(W[(k0 + j) * N + n]);
}

// ---------- MFMA GEMM: C[M,N] = A[M,K](bf16) @ W(repacked bf16), f32 out ----------
template<int K, int N>
__global__ __launch_bounds__(256)
void k_gemm(const unsigned short* __restrict__ A,
            const unsigned short* __restrict__ Wp,
            float* __restrict__ C, int M) {
    constexpr int KSTEPS = K / 32;
    constexpr int NT = N / 16;
    int t = threadIdx.x;
    int w = t >> 6, l = t & 63;
    int m0 = blockIdx.x * 64 + w * 16;
    int row = m0 + (l & 15);
    long arow = (row < M) ? row : (M - 1);
    const unsigned short* Ap = A + arow * K + ((l >> 4) * 8);
    const short8* Bp = (const short8*)Wp + l;

    float4v acc[NT];
#pragma unroll
    for (int j = 0; j < NT; j++) acc[j] = (float4v){0.f, 0.f, 0.f, 0.f};

#pragma unroll
    for (int s = 0; s < KSTEPS; s++) {
        short8 af = *(const short8*)(Ap + s * 32);
#pragma unroll
        for (int j = 0; j < NT; j++) {
            short8 bf = Bp[(s * NT + j) * 64];
            acc[j] = __builtin_amdgcn_mfma_f32_16x16x32_bf16(af, bf, acc[j], 0, 0, 0);
        }
    }
    int col = l & 15;
    int rb = (l >> 4) * 4;
#pragma unroll
    for (int r = 0; r < 4; r++) {
        int rr = m0 + rb + r;
        if (rr < M) {
#pragma unroll
            for (int j = 0; j < NT; j++)
                C[(long)rr * N + j * 16 + col] = acc[j][r];
        }
    }
}

// ---------- column stats accumulation ----------
__global__ __launch_bounds__(256)
void k_colstats_acc(const float* __restrict__ X, int total, int cmask,
                    float* __restrict__ acc, float* __restrict__ accsq) {
    int T  = blockIdx.x * 256 + threadIdx.x;
    int TT = gridDim.x * 256;
    float s = 0.f, sq = 0.f;
    for (int i = T; i < total; i += TT) {
        float v = X[i];
        s += v; sq += v * v;
    }
    __shared__ float ls[256], lq[256];
    int tid = threadIdx.x;
    ls[tid] = s; lq[tid] = sq;
    __syncthreads();
    int ncols = cmask + 1;
    for (int off = 128; off >= ncols; off >>= 1) {
        if (tid < off) { ls[tid] += ls[tid + off]; lq[tid] += lq[tid + off]; }
        __syncthreads();
    }
    if (tid < ncols) {
        atomicAdd(&acc[tid],   ls[tid]);
        atomicAdd(&accsq[tid], lq[tid]);
    }
}

__global__ __launch_bounds__(256)
void k_finstats(const float* __restrict__ acc, const float* __restrict__ accsq,
                const float* __restrict__ g, const float* __restrict__ b,
                float* __restrict__ scale, float* __restrict__ shift,
                int ncols, float inv_n) {
    int c = threadIdx.x;
    if (c < ncols) {
        float m   = acc[c] * inv_n;
        float var = accsq[c] * inv_n - m * m;
        float sc  = g[c] * rsqrtf(var + EPSV);
        scale[c] = sc;
        shift[c] = b[c] - sc * m;
    }
}

// ---------- BN + lrelu in place (f32) ----------
__global__ __launch_bounds__(256)
void k_bnlrelu(float* __restrict__ X, const float* __restrict__ sc,
               const float* __restrict__ sh, int cmask, int total) {
    int T  = blockIdx.x * 256 + threadIdx.x;
    int TT = gridDim.x * 256;
    for (int i = T; i < total; i += TT) {
        int c = i & cmask;
        float v = X[i] * sc[c] + sh[c];
        X[i] = (v >= 0.f) ? v : SLOPE * v;
    }
}

// ---------- BN + lrelu -> bf16 copy ----------
__global__ __launch_bounds__(256)
void k_bnlrelu_tobf(const float* __restrict__ X, unsigned short* __restrict__ Y,
                    const float* __restrict__ sc, const float* __restrict__ sh,
                    int cmask, int total) {
    int T  = blockIdx.x * 256 + threadIdx.x;
    int TT = gridDim.x * 256;
    for (int i = T; i < total; i += TT) {
        int c = i & cmask;
        float v = X[i] * sc[c] + sh[c];
        v = (v >= 0.f) ? v : SLOPE * v;
        Y[i] = f2bf(v);
    }
}

// ---------- fused KPConv: 16 points/block, MFMA aggregation ----------
__global__ __launch_bounds__(256)
void k_kpconv(const float* __restrict__ qpts, const float* __restrict__ spts,
              const int* __restrict__ nbr, const float* __restrict__ x1,
              const float* __restrict__ kpp, const unsigned short* __restrict__ kwp,
              float* __restrict__ y) {
    __shared__ __align__(16) unsigned short wfs[16][968]; // 960 + 8 pad (bank-conflict break)
    __shared__ float infl[4][HN][16];
    __shared__ int   sidx[4][HN];

    int t = threadIdx.x;
    int w = t >> 6, l = t & 63;

    for (int pp = 0; pp < 4; pp++) {
        int p = w * 4 + pp;
        int n = blockIdx.x * 16 + p;

        // phase 1: influences (lanes 0..31)
        if (l < HN) {
            int idx = nbr[n * HN + l];
            sidx[w][l] = idx;
            float qx = qpts[n * 3 + 0], qy = qpts[n * 3 + 1], qz = qpts[n * 3 + 2];
            float dx = spts[idx * 3 + 0] - qx;
            float dy = spts[idx * 3 + 1] - qy;
            float dz = spts[idx * 3 + 2] - qz;
#pragma unroll
            for (int k = 0; k < KP; k++) {
                float ex = dx - kpp[k * 3 + 0];
                float ey = dy - kpp[k * 3 + 1];
                float ez = dz - kpp[k * 3 + 2];
                float sq = ex * ex + ey * ey + ez * ez;
                float dist = sqrtf(fmaxf(sq, 1e-12f));
                infl[w][l][k] = fmaxf(0.f, 1.f - dist * (1.f / KPE));
            }
            infl[w][l][15] = 0.f;
        }
        // wave-synchronous: LDS ops within a wave are ordered; no barrier needed

        // phase 2: wf[k][d] = sum_h infl[h][k] * x1[idx_h][d]; lane = d
        float wfa[KP];
#pragma unroll
        for (int k = 0; k < KP; k++) wfa[k] = 0.f;

        for (int h = 0; h < HN; h++) {
            int idx = sidx[w][h];
            float v = x1[(long)idx * MIDF + l];
            const float4* ip = (const float4*)(&infl[w][h][0]);
            float4 i0 = ip[0], i1 = ip[1], i2 = ip[2], i3 = ip[3];
            wfa[0]  += i0.x * v;  wfa[1]  += i0.y * v;  wfa[2]  += i0.z * v;  wfa[3]  += i0.w * v;
            wfa[4]  += i1.x * v;  wfa[5]  += i1.y * v;  wfa[6]  += i1.z * v;  wfa[7]  += i1.w * v;
            wfa[8]  += i2.x * v;  wfa[9]  += i2.y * v;  wfa[10] += i2.z * v;  wfa[11] += i2.w * v;
            wfa[12] += i3.x * v;  wfa[13] += i3.y * v;  wfa[14] += i3.z * v;
        }
#pragma unroll
        for (int k = 0; k < KP; k++)
            wfs[p][k * 64 + l] = f2bf(wfa[k]);
        if (l < 8) wfs[p][960 + l] = 0;  // pad region
    }
    __syncthreads();

    // phase 3: y[16pts][64] = wf[16][960] @ kw[960][64]; wave w -> col-tile w
    float4v acc = (float4v){0.f, 0.f, 0.f, 0.f};
    const unsigned short* arow = &wfs[l & 15][0] + (l >> 4) * 8;
    const short8* Bp = (const short8*)kwp + l;
#pragma unroll 6
    for (int s = 0; s < 30; s++) {
        short8 af = *(const short8*)(arow + s * 32);
        short8 bf = Bp[(s * 4 + w) * 64];
        acc = __builtin_amdgcn_mfma_f32_16x16x32_bf16(af, bf, acc, 0, 0, 0);
    }
    int col = l & 15;
    int rb = (l >> 4) * 4;
#pragma unroll
    for (int r = 0; r < 4; r++)
        y[(long)(blockIdx.x * 16 + rb + r) * MIDF + w * 16 + col] = acc[r];
}

// ---------- final: lrelu(lrelu_bn(x3) + lrelu_bn(sc)) ----------
__global__ __launch_bounds__(256)
void k_final(const float* __restrict__ x3, float* __restrict__ out,
             const float* __restrict__ s3, const float* __restrict__ h3,
             const float* __restrict__ sS, const float* __restrict__ hS,
             int total) {
    int T  = blockIdx.x * 256 + threadIdx.x;
    int TT = gridDim.x * 256;
    for (int i = T; i < total; i += TT) {
        int c = i & 255;
        float a = x3[i] * s3[c] + h3[c];
        a = (a >= 0.f) ? a : SLOPE * a;
        float b = out[i] * sS[c] + hS[c];
        b = (b >= 0.f) ? b : SLOPE * b;
        float v = a + b;
        out[i] = (v >= 0.f) ? v : SLOPE * v;
    }
}

extern "C" void kernel_launch(void* const* d_in, const int* in_sizes, int n_in,
                              void* d_out, int out_size, void* d_ws, size_t ws_size,
                              hipStream_t stream) {
    const float* qp   = (const float*)d_in[0];
    const float* sp   = (const float*)d_in[1];
    const int*   nbr  = (const int*)d_in[2];
    const float* feat = (const float*)d_in[3];
    const float* kpp  = (const float*)d_in[4];
    const float* w1   = (const float*)d_in[5];
    const float* g1   = (const float*)d_in[6];
    const float* b1   = (const float*)d_in[7];
    const float* kw   = (const float*)d_in[8];
    const float* g2   = (const float*)d_in[9];
    const float* b2   = (const float*)d_in[10];
    const float* w3   = (const float*)d_in[11];
    const float* g3   = (const float*)d_in[12];
    const float* b3   = (const float*)d_in[13];
    const float* wsw  = (const float*)d_in[14];
    const float* gs   = (const float*)d_in[15];
    const float* bs   = (const float*)d_in[16];
    float* out = (float*)d_out;

    char* base = (char*)d_ws;
    // x3 occupies [0, 51.2MB); x1 aliases its first 12.8MB, x2 the next 12.8MB
    float* x3 = (float*)base;
    float* x1 = (float*)base;                       // dead before conv3 writes x3
    float* x2 = (float*)(base + 12800000);          // dead before conv3 writes x3
    unsigned short* featb = (unsigned short*)(base + 51200000);  // 12.8MB
    unsigned short* x2b   = (unsigned short*)(base + 64000000);  // 6.4MB
    unsigned short* wp1   = (unsigned short*)(base + 70400000);  // 16KB
    unsigned short* wpk   = (unsigned short*)(base + 70416384);  // 120KB
    unsigned short* wp3   = (unsigned short*)(base + 70539264);  // 32KB
    unsigned short* wpS   = (unsigned short*)(base + 70572032);  // 64KB
    float* st = (float*)(base + 70637568);
    float* acc1 = st +    0, *q1 = st +   64;
    float* acc2 = st +  128, *q2 = st +  192;
    float* acc3 = st +  256, *q3 = st +  512;
    float* accS = st +  768, *qS = st + 1024;
    float* s1 = st + 1280, *h1 = st + 1344;
    float* s2 = st + 1408, *h2 = st + 1472;
    float* s3 = st + 1536, *h3 = st + 1792;
    float* sS = st + 2048, *hS = st + 2304;

    hipMemsetAsync(st, 0, 1280 * sizeof(float), stream);

    const float invN = 1.f / (float)NPTS;

    // weight repack + feat conversion
    k_repack<<<4, 256, 0, stream>>>(w1, wp1, INF1, MIDF);       // 1024 ids
    k_repack<<<30, 256, 0, stream>>>(kw, wpk, KP * MIDF, MIDF); // 7680 ids
    k_repack<<<8, 256, 0, stream>>>(w3, wp3, MIDF, OUTF3);      // 2048 ids
    k_repack<<<16, 256, 0, stream>>>(wsw, wpS, INF1, OUTF3);    // 4096 ids
    k_tobf<<<6250, 256, 0, stream>>>(feat, featb, NPTS * INF1);

    // conv1: x1 = lrelu(bn(feat @ w1))
    k_gemm<INF1, MIDF><<<782, 256, 0, stream>>>(featb, wp1, x1, NPTS);
    k_colstats_acc<<<1024, 256, 0, stream>>>(x1, NPTS * MIDF, 63, acc1, q1);
    k_finstats<<<1, 256, 0, stream>>>(acc1, q1, g1, b1, s1, h1, MIDF, invN);
    k_bnlrelu<<<2048, 256, 0, stream>>>(x1, s1, h1, 63, NPTS * MIDF);

    // conv2: fused KPConv (gather + influence -> LDS wf -> MFMA vs kw)
    k_kpconv<<<NPTS / 16, 256, 0, stream>>>(qp, sp, nbr, x1, kpp, wpk, x2);
    k_colstats_acc<<<1024, 256, 0, stream>>>(x2, NPTS * MIDF, 63, acc2, q2);
    k_finstats<<<1, 256, 0, stream>>>(acc2, q2, g2, b2, s2, h2, MIDF, invN);
    k_bnlrelu_tobf<<<2048, 256, 0, stream>>>(x2, x2b, s2, h2, 63, NPTS * MIDF);

    // conv3: x3 = x2b @ w3 (BN folded into final)
    k_gemm<MIDF, OUTF3><<<782, 256, 0, stream>>>(x2b, wp3, x3, NPTS);
    k_colstats_acc<<<1024, 256, 0, stream>>>(x3, NPTS * OUTF3, 255, acc3, q3);
    k_finstats<<<1, 256, 0, stream>>>(acc3, q3, g3, b3, s3, h3, OUTF3, invN);

    // shortcut: out = feat @ ws
    k_gemm<INF1, OUTF3><<<782, 256, 0, stream>>>(featb, wpS, out, NPTS);
    k_colstats_acc<<<1024, 256, 0, stream>>>(out, NPTS * OUTF3, 255, accS, qS);
    k_finstats<<<1, 256, 0, stream>>>(accS, qS, gs, bs, sS, hS, OUTF3, invN);

    // final combine
    k_final<<<4096, 256, 0, stream>>>(x3, out, s3, h3, sS, hS, NPTS * OUTF3);
}

// Round 3
// 355.853 us; speedup vs baseline: 2.4011x; 1.2554x over previous
//
#include <hip/hip_runtime.h>

#define NPTS 50000
#define HN 32
#define INF1 128
#define OUTF3 256
#define MIDF 64
#define KP 15
#define EPSV 1e-6f
#define SLOPE 0.1f
#define KPE 0.48f   // 1.2 * 2.0 / 5.0
#define INVN (1.f / 50000.f)

typedef __attribute__((ext_vector_type(8))) short short8;   // 8 bf16
typedef __attribute__((ext_vector_type(4))) float float4v;  // MFMA acc
typedef unsigned short ushort;
typedef unsigned long long ull;

__device__ inline ushort f2bf(float f) {
    union { float f; unsigned u; } v; v.f = f;
    unsigned r = v.u + 0x7fff + ((v.u >> 16) & 1);
    return (ushort)(r >> 16);
}
__device__ inline float bf2f(ushort u) {
    union { unsigned u; float f; } v; v.u = ((unsigned)u) << 16;
    return v.f;
}

// ---------- repack all 4 weights f32 -> B-fragment bf16 in one launch ----------
// Wp[s][nt][lane][8]: lane wants B[k=s*32+((l>>4)&3)*8+j][n=nt*16+(l&15)]
__device__ inline void repack_one(const float* W, ushort* Wp, int K, int N, int lid) {
    int l  = lid & 63;
    int NT = N / 16;
    int nt = (lid >> 6) % NT;
    int s  = lid / (64 * NT);
    int n  = nt * 16 + (l & 15);
    int k0 = s * 32 + ((l >> 4) & 3) * 8;
#pragma unroll
    for (int j = 0; j < 8; j++)
        Wp[lid * 8 + j] = f2bf(W[(k0 + j) * N + n]);
}

__global__ __launch_bounds__(256)
void k_repack_all(const float* __restrict__ w1, ushort* __restrict__ wp1,
                  const float* __restrict__ kw, ushort* __restrict__ wpk,
                  const float* __restrict__ w3, ushort* __restrict__ wp3,
                  const float* __restrict__ wsw, ushort* __restrict__ wpS) {
    int id = blockIdx.x * 256 + threadIdx.x;
    if (id < 1024)        repack_one(w1,  wp1, INF1,      MIDF,  id);
    else if (id < 8704)   repack_one(kw,  wpk, KP * MIDF, MIDF,  id - 1024);
    else if (id < 10752)  repack_one(w3,  wp3, MIDF,      OUTF3, id - 8704);
    else if (id < 14848)  repack_one(wsw, wpS, INF1,      OUTF3, id - 10752);
}

// ---------- MFMA GEMM with fused column-stats epilogue ----------
// A: f32 (cvt in kernel) or bf16; C: f32 or bf16. Block = 64 rows.
template<int K, int N, bool A16, bool C16, bool STATS>
__global__ __launch_bounds__(256)
void k_gemm(const ushort* __restrict__ Ab, const float* __restrict__ Af,
            const ushort* __restrict__ Wp,
            float* __restrict__ Cf, ushort* __restrict__ Cb,
            float* __restrict__ Sa, float* __restrict__ Sq, int M) {
    constexpr int KSTEPS = K / 32;
    constexpr int NT = N / 16;
    __shared__ float sred[N], qred[N];
    int t = threadIdx.x;
    int w = t >> 6, l = t & 63;

    if (STATS) {
        for (int c = t; c < N; c += 256) { sred[c] = 0.f; qred[c] = 0.f; }
        __syncthreads();
    }

    int m0 = blockIdx.x * 64 + w * 16;
    int row = m0 + (l & 15);
    long arow = (row < M) ? row : (M - 1);
    int aoff = (l >> 4) * 8;
    const short8* Bp = (const short8*)Wp + l;

    float4v acc[NT];
#pragma unroll
    for (int j = 0; j < NT; j++) acc[j] = (float4v){0.f, 0.f, 0.f, 0.f};

#pragma unroll
    for (int s = 0; s < KSTEPS; s++) {
        short8 af;
        if (A16) {
            af = *(const short8*)(Ab + arow * K + aoff + s * 32);
        } else {
            const float* ap = Af + arow * K + aoff + s * 32;
            float4 a0 = *(const float4*)(ap);
            float4 a1 = *(const float4*)(ap + 4);
            union { short8 v; ushort u[8]; } au;
            au.u[0] = f2bf(a0.x); au.u[1] = f2bf(a0.y); au.u[2] = f2bf(a0.z); au.u[3] = f2bf(a0.w);
            au.u[4] = f2bf(a1.x); au.u[5] = f2bf(a1.y); au.u[6] = f2bf(a1.z); au.u[7] = f2bf(a1.w);
            af = au.v;
        }
#pragma unroll
        for (int j = 0; j < NT; j++) {
            short8 bf = Bp[(s * NT + j) * 64];
            acc[j] = __builtin_amdgcn_mfma_f32_16x16x32_bf16(af, bf, acc[j], 0, 0, 0);
        }
    }

    int col = l & 15;
    int rb = (l >> 4) * 4;
#pragma unroll
    for (int r = 0; r < 4; r++) {
        int rr = m0 + rb + r;
        if (rr < M) {
#pragma unroll
            for (int j = 0; j < NT; j++) {
                if (C16) Cb[(long)rr * N + j * 16 + col] = f2bf(acc[j][r]);
                else     Cf[(long)rr * N + j * 16 + col] = acc[j][r];
            }
        }
    }

    if (STATS) {
#pragma unroll
        for (int j = 0; j < NT; j++) {
            float s = 0.f, q = 0.f;
#pragma unroll
            for (int r = 0; r < 4; r++) {
                float v = ((m0 + rb + r) < M) ? acc[j][r] : 0.f;
                s += v; q += v * v;
            }
            s += __shfl_xor(s, 16); s += __shfl_xor(s, 32);
            q += __shfl_xor(q, 16); q += __shfl_xor(q, 32);
            if ((l >> 4) == 0) {
                atomicAdd(&sred[j * 16 + col], s);
                atomicAdd(&qred[j * 16 + col], q);
            }
        }
        __syncthreads();
        for (int c = t; c < N; c += 256) {
            atomicAdd(&Sa[c], sred[c]);
            atomicAdd(&Sq[c], qred[c]);
        }
    }
}

// ---------- BN + lrelu: bf16 -> bf16, inline finstats, 64 cols ----------
__global__ __launch_bounds__(256)
void k_bnx(const ushort* __restrict__ X, ushort* __restrict__ Y,
           const float* __restrict__ Sa, const float* __restrict__ Sq,
           const float* __restrict__ g, const float* __restrict__ b) {
    __shared__ float sc[64], sh[64];
    int t = threadIdx.x;
    if (t < 64) {
        float m = Sa[t] * INVN;
        float v = Sq[t] * INVN - m * m;
        float s = g[t] * rsqrtf(v + EPSV);
        sc[t] = s; sh[t] = b[t] - s * m;
    }
    __syncthreads();
    long i = (long)(blockIdx.x * 256 + t) * 4;
    ull vin = *(const ull*)(X + i);
    int c0 = (int)(i & 63);
    ull vout = 0;
#pragma unroll
    for (int j = 0; j < 4; j++) {
        float f = bf2f((ushort)((vin >> (16 * j)) & 0xffff));
        float v = f * sc[c0 + j] + sh[c0 + j];
        v = (v >= 0.f) ? v : SLOPE * v;
        vout |= ((ull)f2bf(v)) << (16 * j);
    }
    *(ull*)(Y + i) = vout;
}

// ---------- fused KPConv: all-MFMA, 16 points/block ----------
__global__ __launch_bounds__(256)
void k_kpconv(const float* __restrict__ qpts, const float* __restrict__ spts,
              const int* __restrict__ nbr, const ushort* __restrict__ x1b,
              const float* __restrict__ kpp, const ushort* __restrict__ kwp,
              ushort* __restrict__ y, float* __restrict__ Sa, float* __restrict__ Sq) {
    __shared__ __align__(16) ushort wfs[16][968];   // [p][kd], pitch 968 breaks conflicts
    __shared__ float posd[4][3][HN];                // per-wave neighbor deltas
    __shared__ int   sidx[4][HN];

    int t = threadIdx.x;
    int w = t >> 6, l = t & 63;
    int dl = l & 15;
    int q4 = l >> 4;

    // per-lane kernel point (A-frag m index); k==15 is the pad row -> influence 0
    int kq = dl;
    int kmin = (kq < 15) ? kq : 14;
    float kx = kpp[kmin * 3 + 0], ky = kpp[kmin * 3 + 1], kz = kpp[kmin * 3 + 2];

    for (int pp = 0; pp < 4; pp++) {
        int p = w * 4 + pp;
        int n = blockIdx.x * 16 + p;

        // stage neighbor indices + deltas (lanes 0..31), wave-synchronous
        if (l < HN) {
            int idx = nbr[n * HN + l];
            sidx[w][l] = idx;
            float qx = qpts[n * 3 + 0], qy = qpts[n * 3 + 1], qz = qpts[n * 3 + 2];
            posd[w][0][l] = spts[idx * 3 + 0] - qx;
            posd[w][1][l] = spts[idx * 3 + 1] - qy;
            posd[w][2][l] = spts[idx * 3 + 2] - qz;
        }

        // A-frag: influences, lane l owns A[m=kq][h=q4*8+j]
        union { short8 v; ushort u[8]; } afr;
#pragma unroll
        for (int j = 0; j < 8; j++) {
            int h = q4 * 8 + j;
            float ex = posd[w][0][h] - kx;
            float ey = posd[w][1][h] - ky;
            float ez = posd[w][2][h] - kz;
            float sq = ex * ex + ey * ey + ez * ez;
            float dist = sqrtf(fmaxf(sq, 1e-12f));
            float inf = fmaxf(0.f, 1.f - dist * (1.f / KPE));
            afr.u[j] = (kq < 15) ? f2bf(inf) : (ushort)0;
        }

        // B-frag: gather x1b[idx[h]][d] in fragment order (bf16, no conversion)
        int ridx[8];
#pragma unroll
        for (int j = 0; j < 8; j++) ridx[j] = sidx[w][q4 * 8 + j] * MIDF;
        union { short8 v; ushort u[8]; } bfr[4];
#pragma unroll
        for (int nt = 0; nt < 4; nt++)
#pragma unroll
            for (int j = 0; j < 8; j++)
                bfr[nt].u[j] = x1b[ridx[j] + nt * 16 + dl];

        // wf[16 kpts][64 d] via 4 MFMA
        float4v wfacc[4];
#pragma unroll
        for (int nt = 0; nt < 4; nt++)
            wfacc[nt] = __builtin_amdgcn_mfma_f32_16x16x32_bf16(
                afr.v, bfr[nt].v, (float4v){0.f, 0.f, 0.f, 0.f}, 0, 0, 0);

        // write wf to LDS in [kd] order; quarter-rotated nt to dodge bank conflicts
#pragma unroll
        for (int ntx = 0; ntx < 4; ntx++) {
            int nt = (ntx + q4) & 3;
#pragma unroll
            for (int r = 0; r < 4; r++) {
                int k = q4 * 4 + r;
                if (k < 15)
                    wfs[p][k * 64 + nt * 16 + dl] = f2bf(wfacc[nt][r]);
            }
        }
    }
    __syncthreads();

    // phase 3: y[16][64] = wf[16][960] @ kw[960][64]; wave w -> col tile w
    float4v acc = (float4v){0.f, 0.f, 0.f, 0.f};
    const ushort* arow = &wfs[dl][0] + q4 * 8;
    const short8* Bp = (const short8*)kwp + l;
#pragma unroll 6
    for (int s = 0; s < 30; s++) {
        short8 af = *(const short8*)(arow + s * 32);
        short8 bf = Bp[(s * 4 + w) * 64];
        acc = __builtin_amdgcn_mfma_f32_16x16x32_bf16(af, bf, acc, 0, 0, 0);
    }

    // store bf16 + fused stats
    int o = w * 16 + dl;
    float s = 0.f, q = 0.f;
#pragma unroll
    for (int r = 0; r < 4; r++) {
        float v = acc[r];
        y[(long)(blockIdx.x * 16 + q4 * 4 + r) * MIDF + o] = f2bf(v);
        s += v; q += v * v;
    }
    s += __shfl_xor(s, 16); s += __shfl_xor(s, 32);
    q += __shfl_xor(q, 16); q += __shfl_xor(q, 32);
    if (q4 == 0) {
        atomicAdd(&Sa[o], s);
        atomicAdd(&Sq[o], q);
    }
}

// ---------- final: inline finstats, lrelu(lrelu_bn(x3) + lrelu_bn(sc)) ----------
__global__ __launch_bounds__(256)
void k_final(const float* __restrict__ x3, float* __restrict__ out,
             const float* __restrict__ a3, const float* __restrict__ q3,
             const float* __restrict__ g3, const float* __restrict__ b3,
             const float* __restrict__ aS, const float* __restrict__ qS,
             const float* __restrict__ gs, const float* __restrict__ bs) {
    __shared__ float s3[256], h3[256], sS[256], hS[256];
    int t = threadIdx.x;
    {
        float m = a3[t] * INVN;
        float v = q3[t] * INVN - m * m;
        float s = g3[t] * rsqrtf(v + EPSV);
        s3[t] = s; h3[t] = b3[t] - s * m;
        m = aS[t] * INVN;
        v = qS[t] * INVN - m * m;
        s = gs[t] * rsqrtf(v + EPSV);
        sS[t] = s; hS[t] = bs[t] - s * m;
    }
    __syncthreads();
    long i = (long)(blockIdx.x * 256 + t) * 4;
    int c0 = (int)(i & 255);
    float4 a = *(const float4*)(x3 + i);
    float4 o = *(const float4*)(out + i);
    float va[4] = {a.x, a.y, a.z, a.w};
    float vo[4] = {o.x, o.y, o.z, o.w};
#pragma unroll
    for (int j = 0; j < 4; j++) {
        int c = c0 + j;
        float x = va[j] * s3[c] + h3[c];
        x = (x >= 0.f) ? x : SLOPE * x;
        float sc = vo[j] * sS[c] + hS[c];
        sc = (sc >= 0.f) ? sc : SLOPE * sc;
        float v = x + sc;
        va[j] = (v >= 0.f) ? v : SLOPE * v;
    }
    *(float4*)(out + i) = (float4){va[0], va[1], va[2], va[3]};
}

extern "C" void kernel_launch(void* const* d_in, const int* in_sizes, int n_in,
                              void* d_out, int out_size, void* d_ws, size_t ws_size,
                              hipStream_t stream) {
    const float* qp   = (const float*)d_in[0];
    const float* sp   = (const float*)d_in[1];
    const int*   nbr  = (const int*)d_in[2];
    const float* feat = (const float*)d_in[3];
    const float* kpp  = (const float*)d_in[4];
    const float* w1   = (const float*)d_in[5];
    const float* g1   = (const float*)d_in[6];
    const float* b1   = (const float*)d_in[7];
    const float* kw   = (const float*)d_in[8];
    const float* g2   = (const float*)d_in[9];
    const float* b2   = (const float*)d_in[10];
    const float* w3   = (const float*)d_in[11];
    const float* g3   = (const float*)d_in[12];
    const float* b3   = (const float*)d_in[13];
    const float* wsw  = (const float*)d_in[14];
    const float* gs   = (const float*)d_in[15];
    const float* bs   = (const float*)d_in[16];
    float* out = (float*)d_out;

    char* base = (char*)d_ws;
    float*  x3    = (float*)base;                       // 51.2 MB
    ushort* x1raw = (ushort*)base;                      // 6.4 MB (dead before x3)
    ushort* x1b   = (ushort*)(base + 6400000);          // 6.4 MB (dead before x3)
    ushort* x2raw = (ushort*)(base + 12800000);         // 6.4 MB (dead before x3)
    ushort* x2b   = (ushort*)(base + 51200000);         // 6.4 MB (live during gemm3)
    ushort* wp1   = (ushort*)(base + 57600000);
    ushort* wpk   = (ushort*)(base + 57616384);
    ushort* wp3   = (ushort*)(base + 57739264);
    ushort* wpS   = (ushort*)(base + 57772032);
    float*  st    = (float*)(base + 57837568);
    float* acc1 = st, *q1 = st + 64;
    float* acc2 = st + 128, *q2 = st + 192;
    float* acc3 = st + 256, *q3 = st + 512;
    float* accS = st + 768, *qS = st + 1024;

    hipMemsetAsync(st, 0, 1152 * sizeof(float), stream);

    k_repack_all<<<58, 256, 0, stream>>>(w1, wp1, kw, wpk, w3, wp3, wsw, wpS);

    // conv1: x1raw = feat @ w1 (bf16 out, fused stats)
    k_gemm<INF1, MIDF, false, true, true><<<782, 256, 0, stream>>>(
        nullptr, feat, wp1, nullptr, x1raw, acc1, q1, NPTS);
    k_bnx<<<3125, 256, 0, stream>>>(x1raw, x1b, acc1, q1, g1, b1);

    // conv2: fused KPConv (influence-MFMA + gather-MFMA + kw-MFMA), fused stats
    k_kpconv<<<NPTS / 16, 256, 0, stream>>>(qp, sp, nbr, x1b, kpp, wpk, x2raw, acc2, q2);
    k_bnx<<<3125, 256, 0, stream>>>(x2raw, x2b, acc2, q2, g2, b2);

    // conv3: x3 = x2b @ w3 (f32 out, fused stats)
    k_gemm<MIDF, OUTF3, true, false, true><<<782, 256, 0, stream>>>(
        x2b, nullptr, wp3, x3, nullptr, acc3, q3, NPTS);

    // shortcut: out = feat @ ws (f32 out, fused stats)
    k_gemm<INF1, OUTF3, false, false, true><<<782, 256, 0, stream>>>(
        nullptr, feat, wpS, out, nullptr, accS, qS, NPTS);

    // final combine (inline finstats for both BNs)
    k_final<<<12500, 256, 0, stream>>>(x3, out, acc3, q3, g3, b3, accS, qS, gs, bs);
}

// Round 4
// 326.693 us; speedup vs baseline: 2.6154x; 1.0893x over previous
//
#include <hip/hip_runtime.h>

#define NPTS 50000
#define HN 32
#define INF1 128
#define OUTF3 256
#define MIDF 64
#define KP 15
#define EPSV 1e-6f
#define SLOPE 0.1f
#define KPE 0.48f   // 1.2 * 2.0 / 5.0
#define INVN (1.f / 50000.f)

typedef __attribute__((ext_vector_type(8))) short short8;   // 8 bf16
typedef __attribute__((ext_vector_type(4))) float float4v;  // MFMA acc
typedef unsigned short ushort;
typedef unsigned long long ull;

__device__ inline ushort f2bf(float f) {
    union { float f; unsigned u; } v; v.f = f;
    unsigned r = v.u + 0x7fff + ((v.u >> 16) & 1);
    return (ushort)(r >> 16);
}
__device__ inline float bf2f(ushort u) {
    union { unsigned u; float f; } v; v.u = ((unsigned)u) << 16;
    return v.f;
}

// ---------- repack weights f32 -> B-fragment bf16 ----------
// Wp[s][nt][lane][8]: lane wants B[k=s*32+((l>>4)&3)*8+j][n=nt*16+(l&15)]
__device__ inline void repack_one(const float* W, ushort* Wp, int K, int N, int lid) {
    int l  = lid & 63;
    int NT = N / 16;
    int nt = (lid >> 6) % NT;
    int s  = lid / (64 * NT);
    int n  = nt * 16 + (l & 15);
    int k0 = s * 32 + ((l >> 4) & 3) * 8;
#pragma unroll
    for (int j = 0; j < 8; j++)
        Wp[lid * 8 + j] = f2bf(W[(k0 + j) * N + n]);
}

// wpC: merged [w1 | wsw] as K=128, N=320 (cols 0..63 = w1, 64..319 = wsw)
__global__ __launch_bounds__(256)
void k_repack_all(const float* __restrict__ w1, const float* __restrict__ wsw,
                  ushort* __restrict__ wpC,
                  const float* __restrict__ kw, ushort* __restrict__ wpk,
                  const float* __restrict__ w3, ushort* __restrict__ wp3) {
    int id = blockIdx.x * 256 + threadIdx.x;
    if (id < 5120) {
        int l  = id & 63;
        int nt = (id >> 6) % 20;
        int s  = id / 1280;
        int n  = nt * 16 + (l & 15);
        int k0 = s * 32 + ((l >> 4) & 3) * 8;
#pragma unroll
        for (int j = 0; j < 8; j++) {
            float v = (n < 64) ? w1[(k0 + j) * 64 + n] : wsw[(k0 + j) * 256 + (n - 64)];
            wpC[id * 8 + j] = f2bf(v);
        }
    } else if (id < 12800) {
        repack_one(kw, wpk, KP * MIDF, MIDF, id - 5120);
    } else if (id < 14848) {
        repack_one(w3, wp3, MIDF, OUTF3, id - 12800);
    }
}

// ---------- conv1 + shortcut fused GEMM: feat(f32) @ [w1|ws] -> x1raw(bf16), scb(bf16) ----------
__global__ __launch_bounds__(256)
void k_conv1sc(const float* __restrict__ feat, const ushort* __restrict__ WpC,
               ushort* __restrict__ x1raw, ushort* __restrict__ scb,
               float* __restrict__ Sa1, float* __restrict__ Sq1,
               float* __restrict__ SaS, float* __restrict__ SqS, int M) {
    constexpr int KSTEPS = 4, NT = 20;
    __shared__ float sred[320], qred[320];
    int t = threadIdx.x;
    int w = t >> 6, l = t & 63;
    int dl = l & 15, q4 = l >> 4;

    for (int c = t; c < 320; c += 256) { sred[c] = 0.f; qred[c] = 0.f; }
    __syncthreads();

    int m0 = blockIdx.x * 64 + w * 16;
    int row = m0 + dl;
    long arow = (row < M) ? row : (M - 1);
    const float* ap0 = feat + arow * INF1 + q4 * 8;
    const short8* Bp = (const short8*)WpC + l;

    float4v acc[NT];
#pragma unroll
    for (int j = 0; j < NT; j++) acc[j] = (float4v){0.f, 0.f, 0.f, 0.f};

#pragma unroll
    for (int s = 0; s < KSTEPS; s++) {
        const float* ap = ap0 + s * 32;
        float4 a0 = *(const float4*)(ap);
        float4 a1 = *(const float4*)(ap + 4);
        union { short8 v; ushort u[8]; } au;
        au.u[0] = f2bf(a0.x); au.u[1] = f2bf(a0.y); au.u[2] = f2bf(a0.z); au.u[3] = f2bf(a0.w);
        au.u[4] = f2bf(a1.x); au.u[5] = f2bf(a1.y); au.u[6] = f2bf(a1.z); au.u[7] = f2bf(a1.w);
#pragma unroll
        for (int j = 0; j < NT; j++) {
            short8 bf = Bp[(s * NT + j) * 64];
            acc[j] = __builtin_amdgcn_mfma_f32_16x16x32_bf16(au.v, bf, acc[j], 0, 0, 0);
        }
    }

    int rb = q4 * 4;
#pragma unroll
    for (int r = 0; r < 4; r++) {
        int rr = m0 + rb + r;
        if (rr < M) {
#pragma unroll
            for (int j = 0; j < NT; j++) {
                int c = j * 16 + dl;
                ushort v = f2bf(acc[j][r]);
                if (c < 64) x1raw[(long)rr * 64 + c] = v;
                else        scb[(long)rr * 256 + (c - 64)] = v;
            }
        }
    }

#pragma unroll
    for (int j = 0; j < NT; j++) {
        float s = 0.f, q = 0.f;
#pragma unroll
        for (int r = 0; r < 4; r++) {
            float v = ((m0 + rb + r) < M) ? acc[j][r] : 0.f;
            s += v; q += v * v;
        }
        s += __shfl_xor(s, 16); s += __shfl_xor(s, 32);
        q += __shfl_xor(q, 16); q += __shfl_xor(q, 32);
        if (q4 == 0) {
            atomicAdd(&sred[j * 16 + dl], s);
            atomicAdd(&qred[j * 16 + dl], q);
        }
    }
    __syncthreads();
    for (int c = t; c < 320; c += 256) {
        if (c < 64) { atomicAdd(&Sa1[c], sred[c]); atomicAdd(&Sq1[c], qred[c]); }
        else        { atomicAdd(&SaS[c - 64], sred[c]); atomicAdd(&SqS[c - 64], qred[c]); }
    }
}

// ---------- conv3 GEMM with inline BN2+lrelu on A and fused stats: x3b bf16 ----------
__global__ __launch_bounds__(256)
void k_conv3(const ushort* __restrict__ x2raw, const ushort* __restrict__ Wp,
             ushort* __restrict__ x3b,
             const float* __restrict__ Sa2, const float* __restrict__ Sq2,
             const float* __restrict__ g2, const float* __restrict__ b2,
             float* __restrict__ Sa3, float* __restrict__ Sq3, int M) {
    constexpr int NT = 16;
    __shared__ float sred[256], qred[256];
    __shared__ float scs[64], shs[64];
    int t = threadIdx.x;
    int w = t >> 6, l = t & 63;
    int dl = l & 15, q4 = l >> 4;

    if (t < 64) {
        float m = Sa2[t] * INVN;
        float v = Sq2[t] * INVN - m * m;
        float s = g2[t] * rsqrtf(v + EPSV);
        scs[t] = s; shs[t] = b2[t] - s * m;
    }
    if (t < 256) { sred[t] = 0.f; qred[t] = 0.f; }
    __syncthreads();

    int m0 = blockIdx.x * 64 + w * 16;
    int row = m0 + dl;
    long arow = (row < M) ? row : (M - 1);
    const ushort* ap0 = x2raw + arow * MIDF + q4 * 8;
    const short8* Bp = (const short8*)Wp + l;

    float4v acc[NT];
#pragma unroll
    for (int j = 0; j < NT; j++) acc[j] = (float4v){0.f, 0.f, 0.f, 0.f};

#pragma unroll
    for (int s = 0; s < 2; s++) {
        union { short8 v; ushort u[8]; } raw;
        raw.v = *(const short8*)(ap0 + s * 32);
        const float* scv = &scs[s * 32 + q4 * 8];
        const float* shv = &shs[s * 32 + q4 * 8];
        union { short8 v; ushort u[8]; } au;
#pragma unroll
        for (int e = 0; e < 8; e++) {
            float f = bf2f(raw.u[e]) * scv[e] + shv[e];
            f = (f >= 0.f) ? f : SLOPE * f;
            au.u[e] = f2bf(f);
        }
#pragma unroll
        for (int j = 0; j < NT; j++) {
            short8 bf = Bp[(s * NT + j) * 64];
            acc[j] = __builtin_amdgcn_mfma_f32_16x16x32_bf16(au.v, bf, acc[j], 0, 0, 0);
        }
    }

    int rb = q4 * 4;
#pragma unroll
    for (int r = 0; r < 4; r++) {
        int rr = m0 + rb + r;
        if (rr < M) {
#pragma unroll
            for (int j = 0; j < NT; j++)
                x3b[(long)rr * 256 + j * 16 + dl] = f2bf(acc[j][r]);
        }
    }

#pragma unroll
    for (int j = 0; j < NT; j++) {
        float s = 0.f, q = 0.f;
#pragma unroll
        for (int r = 0; r < 4; r++) {
            float v = ((m0 + rb + r) < M) ? acc[j][r] : 0.f;
            s += v; q += v * v;
        }
        s += __shfl_xor(s, 16); s += __shfl_xor(s, 32);
        q += __shfl_xor(q, 16); q += __shfl_xor(q, 32);
        if (q4 == 0) {
            atomicAdd(&sred[j * 16 + dl], s);
            atomicAdd(&qred[j * 16 + dl], q);
        }
    }
    __syncthreads();
    if (t < 256) {
        atomicAdd(&Sa3[t], sred[t]);
        atomicAdd(&Sq3[t], qred[t]);
    }
}

// ---------- BN + lrelu: bf16 -> bf16, inline finstats, 64 cols ----------
__global__ __launch_bounds__(256)
void k_bnx(const ushort* __restrict__ X, ushort* __restrict__ Y,
           const float* __restrict__ Sa, const float* __restrict__ Sq,
           const float* __restrict__ g, const float* __restrict__ b) {
    __shared__ float sc[64], sh[64];
    int t = threadIdx.x;
    if (t < 64) {
        float m = Sa[t] * INVN;
        float v = Sq[t] * INVN - m * m;
        float s = g[t] * rsqrtf(v + EPSV);
        sc[t] = s; sh[t] = b[t] - s * m;
    }
    __syncthreads();
    long i = (long)(blockIdx.x * 256 + t) * 4;
    ull vin = *(const ull*)(X + i);
    int c0 = (int)(i & 63);
    ull vout = 0;
#pragma unroll
    for (int j = 0; j < 4; j++) {
        float f = bf2f((ushort)((vin >> (16 * j)) & 0xffff));
        float v = f * sc[c0 + j] + sh[c0 + j];
        v = (v >= 0.f) ? v : SLOPE * v;
        vout |= ((ull)f2bf(v)) << (16 * j);
    }
    *(ull*)(Y + i) = vout;
}

// ---------- fused KPConv: LDS-staged gather + all-MFMA, 16 points/block ----------
__global__ __launch_bounds__(256)
void k_kpconv(const float* __restrict__ qpts, const float* __restrict__ spts,
              const int* __restrict__ nbr, const ushort* __restrict__ x1b,
              const float* __restrict__ kpp, const ushort* __restrict__ kwp,
              ushort* __restrict__ y, float* __restrict__ Sa, float* __restrict__ Sq) {
    __shared__ __align__(16) ushort wfs[16][968];   // [p][kd]
    __shared__ __align__(16) ushort fst[4][HN][68]; // per-wave staged rows, pitch 68
    __shared__ float posd[4][3][HN];
    __shared__ int   sidx[4][HN];

    int t = threadIdx.x;
    int w = t >> 6, l = t & 63;
    int dl = l & 15, q4 = l >> 4;
    int hrow = l >> 3, seg = l & 7;

    int kmin = (dl < 15) ? dl : 14;
    float kx = kpp[kmin * 3 + 0], ky = kpp[kmin * 3 + 1], kz = kpp[kmin * 3 + 2];

    for (int pp = 0; pp < 4; pp++) {
        int p = w * 4 + pp;
        int n = blockIdx.x * 16 + p;

        // neighbor indices + deltas (lanes 0..31); wave-synchronous LDS use
        if (l < HN) {
            int idx = nbr[n * HN + l];
            sidx[w][l] = idx;
            float qx = qpts[n * 3 + 0], qy = qpts[n * 3 + 1], qz = qpts[n * 3 + 2];
            posd[w][0][l] = spts[idx * 3 + 0] - qx;
            posd[w][1][l] = spts[idx * 3 + 1] - qy;
            posd[w][2][l] = spts[idx * 3 + 2] - qz;
        }

        // stage 32 neighbor rows (128B each) coalesced: lane -> (row l>>3, 16B seg l&7)
#pragma unroll
        for (int c = 0; c < 4; c++) {
            int h = c * 8 + hrow;
            long r = (long)sidx[w][h] * MIDF + seg * 8;
            uint2 d0 = *(const uint2*)(x1b + r);
            uint2 d1 = *(const uint2*)(x1b + r + 4);
            *(uint2*)&fst[w][h][seg * 8]     = d0;
            *(uint2*)&fst[w][h][seg * 8 + 4] = d1;
        }

        // A-frag: influences, lane owns A[m=dl][h=q4*8+j]
        union { short8 v; ushort u[8]; } afr;
#pragma unroll
        for (int j = 0; j < 8; j++) {
            int h = q4 * 8 + j;
            float ex = posd[w][0][h] - kx;
            float ey = posd[w][1][h] - ky;
            float ez = posd[w][2][h] - kz;
            float sq = ex * ex + ey * ey + ez * ez;
            float dist = sqrtf(fmaxf(sq, 1e-12f));
            float inf = fmaxf(0.f, 1.f - dist * (1.f / KPE));
            afr.u[j] = (dl < 15) ? f2bf(inf) : (ushort)0;
        }

        // B-frags from LDS stage (cheap ds_read_u16, ~2-way conflicts at pitch 68)
        union { short8 v; ushort u[8]; } bfr[4];
#pragma unroll
        for (int nt = 0; nt < 4; nt++)
#pragma unroll
            for (int j = 0; j < 8; j++)
                bfr[nt].u[j] = fst[w][q4 * 8 + j][nt * 16 + dl];

        float4v wfacc[4];
#pragma unroll
        for (int nt = 0; nt < 4; nt++)
            wfacc[nt] = __builtin_amdgcn_mfma_f32_16x16x32_bf16(
                afr.v, bfr[nt].v, (float4v){0.f, 0.f, 0.f, 0.f}, 0, 0, 0);

        // wf -> wfs in [kd] order; quarter-rotated nt to dodge bank conflicts
#pragma unroll
        for (int ntx = 0; ntx < 4; ntx++) {
            int nt = (ntx + q4) & 3;
#pragma unroll
            for (int r = 0; r < 4; r++) {
                int k = q4 * 4 + r;
                if (k < 15)
                    wfs[p][k * 64 + nt * 16 + dl] = f2bf(wfacc[nt][r]);
            }
        }
    }
    __syncthreads();

    // phase 3: y[16][64] = wf[16][960] @ kw[960][64]; wave w -> col tile w
    float4v acc = (float4v){0.f, 0.f, 0.f, 0.f};
    const ushort* arow = &wfs[dl][0] + q4 * 8;
    const short8* Bp = (const short8*)kwp + l;
#pragma unroll 6
    for (int s = 0; s < 30; s++) {
        short8 af = *(const short8*)(arow + s * 32);
        short8 bf = Bp[(s * 4 + w) * 64];
        acc = __builtin_amdgcn_mfma_f32_16x16x32_bf16(af, bf, acc, 0, 0, 0);
    }

    int o = w * 16 + dl;
    float s = 0.f, q = 0.f;
#pragma unroll
    for (int r = 0; r < 4; r++) {
        float v = acc[r];
        y[(long)(blockIdx.x * 16 + q4 * 4 + r) * MIDF + o] = f2bf(v);
        s += v; q += v * v;
    }
    s += __shfl_xor(s, 16); s += __shfl_xor(s, 32);
    q += __shfl_xor(q, 16); q += __shfl_xor(q, 32);
    if (q4 == 0) {
        atomicAdd(&Sa[o], s);
        atomicAdd(&Sq[o], q);
    }
}

// ---------- final: inline finstats, lrelu(lrelu_bn(x3b) + lrelu_bn(scb)) -> f32 ----------
__global__ __launch_bounds__(256)
void k_final(const ushort* __restrict__ x3b, const ushort* __restrict__ scb,
             float* __restrict__ out,
             const float* __restrict__ a3, const float* __restrict__ q3,
             const float* __restrict__ g3, const float* __restrict__ b3,
             const float* __restrict__ aS, const float* __restrict__ qS,
             const float* __restrict__ gs, const float* __restrict__ bs) {
    __shared__ float s3[256], h3[256], sS[256], hS[256];
    int t = threadIdx.x;
    {
        float m = a3[t] * INVN;
        float v = q3[t] * INVN - m * m;
        float s = g3[t] * rsqrtf(v + EPSV);
        s3[t] = s; h3[t] = b3[t] - s * m;
        m = aS[t] * INVN;
        v = qS[t] * INVN - m * m;
        s = gs[t] * rsqrtf(v + EPSV);
        sS[t] = s; hS[t] = bs[t] - s * m;
    }
    __syncthreads();
    long i = (long)(blockIdx.x * 256 + t) * 4;
    int c0 = (int)(i & 255);
    ull va = *(const ull*)(x3b + i);
    ull vb = *(const ull*)(scb + i);
    float r[4];
#pragma unroll
    for (int j = 0; j < 4; j++) {
        int c = c0 + j;
        float x = bf2f((ushort)((va >> (16 * j)) & 0xffff)) * s3[c] + h3[c];
        x = (x >= 0.f) ? x : SLOPE * x;
        float sc = bf2f((ushort)((vb >> (16 * j)) & 0xffff)) * sS[c] + hS[c];
        sc = (sc >= 0.f) ? sc : SLOPE * sc;
        float v = x + sc;
        r[j] = (v >= 0.f) ? v : SLOPE * v;
    }
    *(float4*)(out + i) = (float4){r[0], r[1], r[2], r[3]};
}

extern "C" void kernel_launch(void* const* d_in, const int* in_sizes, int n_in,
                              void* d_out, int out_size, void* d_ws, size_t ws_size,
                              hipStream_t stream) {
    const float* qp   = (const float*)d_in[0];
    const float* sp   = (const float*)d_in[1];
    const int*   nbr  = (const int*)d_in[2];
    const float* feat = (const float*)d_in[3];
    const float* kpp  = (const float*)d_in[4];
    const float* w1   = (const float*)d_in[5];
    const float* g1   = (const float*)d_in[6];
    const float* b1   = (const float*)d_in[7];
    const float* kw   = (const float*)d_in[8];
    const float* g2   = (const float*)d_in[9];
    const float* b2   = (const float*)d_in[10];
    const float* w3   = (const float*)d_in[11];
    const float* g3   = (const float*)d_in[12];
    const float* b3   = (const float*)d_in[13];
    const float* wsw  = (const float*)d_in[14];
    const float* gs   = (const float*)d_in[15];
    const float* bs   = (const float*)d_in[16];
    float* out = (float*)d_out;

    char* base = (char*)d_ws;
    ushort* x1raw = (ushort*)(base + 0);          // 6.4 MB
    ushort* x1b   = (ushort*)(base + 6400000);    // 6.4 MB
    ushort* x2raw = (ushort*)(base + 12800000);   // 6.4 MB
    ushort* x3b   = (ushort*)(base + 19200000);   // 25.6 MB
    ushort* scb   = (ushort*)(base + 44800000);   // 25.6 MB
    ushort* wpC   = (ushort*)(base + 70400000);   // 80 KB
    ushort* wpk   = (ushort*)(base + 70481920);   // 120 KB
    ushort* wp3   = (ushort*)(base + 70604800);   // 32 KB
    float*  st    = (float*)(base + 70637568);
    float* acc1 = st,       *q1 = st + 64;
    float* acc2 = st + 128, *q2 = st + 192;
    float* acc3 = st + 256, *q3 = st + 512;
    float* accS = st + 768, *qS = st + 1024;

    hipMemsetAsync(st, 0, 1280 * sizeof(float), stream);

    k_repack_all<<<58, 256, 0, stream>>>(w1, wsw, wpC, kw, wpk, w3, wp3);

    // conv1 + shortcut fused (feat read once)
    k_conv1sc<<<782, 256, 0, stream>>>(feat, wpC, x1raw, scb, acc1, q1, accS, qS, NPTS);
    k_bnx<<<3125, 256, 0, stream>>>(x1raw, x1b, acc1, q1, g1, b1);

    // KPConv (LDS-staged gather + MFMA), fused stats
    k_kpconv<<<NPTS / 16, 256, 0, stream>>>(qp, sp, nbr, x1b, kpp, wpk, x2raw, acc2, q2);

    // conv3 with inline BN2+lrelu on A, fused stats, bf16 out
    k_conv3<<<782, 256, 0, stream>>>(x2raw, wp3, x3b, acc2, q2, g2, b2, acc3, q3, NPTS);

    // final combine (inline finstats for both BNs)
    k_final<<<12500, 256, 0, stream>>>(x3b, scb, out, acc3, q3, g3, b3, accS, qS, gs, bs);
}

// Round 7
// 301.140 us; speedup vs baseline: 2.8373x; 1.0849x over previous
//
#include <hip/hip_runtime.h>

#define NPTS 50000
#define HN 32
#define INF1 128
#define OUTF3 256
#define MIDF 64
#define KP 15
#define EPSV 1e-6f
#define SLOPE 0.1f
#define KPE 0.48f   // 1.2 * 2.0 / 5.0
#define INVN (1.f / 50000.f)

typedef __attribute__((ext_vector_type(8))) short short8;   // 8 bf16
typedef __attribute__((ext_vector_type(4))) float float4v;  // MFMA acc
typedef unsigned short ushort;
typedef unsigned long long ull;

__device__ inline ushort f2bf(float f) {
    union { float f; unsigned u; } v; v.f = f;
    unsigned r = v.u + 0x7fff + ((v.u >> 16) & 1);
    return (ushort)(r >> 16);
}
__device__ inline float bf2f(ushort u) {
    union { unsigned u; float f; } v; v.u = ((unsigned)u) << 16;
    return v.f;
}

// x1 rows are stored PERMUTED: mem offset m in [0,64) holds original feature
// d(m) = (m&3)*16 + (m>>2).  So a lane with dl = m>>2 reads one b64 (offsets
// 4dl..4dl+3) and gets features {dl, 16+dl, 32+dl, 48+dl} = the 4 B-frag
// elements (nt=0..3) it needs for the gather-MFMA.

// ---------- repack all weights f32 -> B-fragment bf16 ----------
__global__ __launch_bounds__(256)
void k_repack_all(const float* __restrict__ w1, const float* __restrict__ wsw,
                  ushort* __restrict__ wpC,
                  const float* __restrict__ kw, ushort* __restrict__ wpk,
                  const float* __restrict__ w3, ushort* __restrict__ wp3) {
    int id = blockIdx.x * 256 + threadIdx.x;
    if (id < 5120) {                      // wpC: [w1|wsw] K=128 N=320
        int l = id & 63;
        int nt = (id >> 6) % 20, s = id / 1280;
        int n = nt * 16 + (l & 15);
        int k0 = s * 32 + ((l >> 4) & 3) * 8;
#pragma unroll
        for (int j = 0; j < 8; j++) {
            float v = (n < 64) ? w1[(k0 + j) * 64 + n] : wsw[(k0 + j) * 256 + (n - 64)];
            wpC[id * 8 + j] = f2bf(v);
        }
    } else if (id < 13312) {              // wpk: kd = d*16+k (k=15 -> 0), K=1024 N=64
        int id2 = id - 5120;
        int l2 = id2 & 63;
        int nt = (id2 >> 6) & 3, s = id2 >> 8;
        int n = nt * 16 + (l2 & 15);
        int kd0 = s * 32 + ((l2 >> 4) & 3) * 8;
#pragma unroll
        for (int j = 0; j < 8; j++) {
            int kd = kd0 + j, d = kd >> 4, kk = kd & 15;
            float v = (kk < KP) ? kw[kk * 4096 + d * 64 + n] : 0.f;
            wpk[id2 * 8 + j] = f2bf(v);
        }
    } else if (id < 15360) {              // wp3: K=64 N=256
        int id3 = id - 13312;
        int l3 = id3 & 63;
        int nt = (id3 >> 6) % 16, s = id3 / 1024;
        int n = nt * 16 + (l3 & 15);
        int k0 = s * 32 + ((l3 >> 4) & 3) * 8;
#pragma unroll
        for (int j = 0; j < 8; j++)
            wp3[id3 * 8 + j] = f2bf(w3[(k0 + j) * 256 + n]);
    }
}

// ---------- conv1 + shortcut fused GEMM; x1 stored permuted/packed ----------
__global__ __launch_bounds__(256)
void k_conv1sc(const float* __restrict__ feat, const ushort* __restrict__ WpC,
               ushort* __restrict__ x1raw, ushort* __restrict__ scb,
               float* __restrict__ Sa1, float* __restrict__ Sq1,
               float* __restrict__ SaS, float* __restrict__ SqS, int M) {
    __shared__ float sred[320], qred[320];
    int t = threadIdx.x;
    int w = t >> 6, l = t & 63;
    int dl = l & 15, q4 = l >> 4;

    for (int c = t; c < 320; c += 256) { sred[c] = 0.f; qred[c] = 0.f; }
    __syncthreads();

    int m0 = blockIdx.x * 64 + w * 16;
    int row = m0 + dl;
    long arow = (row < M) ? row : (M - 1);
    const float* ap0 = feat + arow * INF1 + q4 * 8;
    short8 afr[4];
#pragma unroll
    for (int s = 0; s < 4; s++) {
        float4 a0 = *(const float4*)(ap0 + s * 32);
        float4 a1 = *(const float4*)(ap0 + s * 32 + 4);
        union { short8 v; ushort u[8]; } au;
        au.u[0] = f2bf(a0.x); au.u[1] = f2bf(a0.y); au.u[2] = f2bf(a0.z); au.u[3] = f2bf(a0.w);
        au.u[4] = f2bf(a1.x); au.u[5] = f2bf(a1.y); au.u[6] = f2bf(a1.z); au.u[7] = f2bf(a1.w);
        afr[s] = au.v;
    }
    const short8* Bp = (const short8*)WpC + l;
    int rb = q4 * 4;
#pragma unroll
    for (int half = 0; half < 2; half++) {
        float4v acc[10];
#pragma unroll
        for (int j = 0; j < 10; j++) acc[j] = (float4v){0.f, 0.f, 0.f, 0.f};
#pragma unroll
        for (int s = 0; s < 4; s++)
#pragma unroll
            for (int j = 0; j < 10; j++) {
                short8 bf = Bp[(s * 20 + half * 10 + j) * 64];
                acc[j] = __builtin_amdgcn_mfma_f32_16x16x32_bf16(afr[s], bf, acc[j], 0, 0, 0);
            }
#pragma unroll
        for (int r = 0; r < 4; r++) {
            int rr = m0 + rb + r;
            if (rr < M) {
                if (half == 0) {
                    // j=0..3 are x1 cols c=j*16+dl -> permuted offset 4*dl+j, packed b64
                    ull pk = 0;
#pragma unroll
                    for (int j = 0; j < 4; j++)
                        pk |= ((ull)f2bf(acc[j][r])) << (16 * j);
                    *(ull*)(x1raw + (long)rr * 64 + 4 * dl) = pk;
#pragma unroll
                    for (int j = 4; j < 10; j++)
                        scb[(long)rr * 256 + (j * 16 + dl - 64)] = f2bf(acc[j][r]);
                } else {
#pragma unroll
                    for (int j = 0; j < 10; j++)
                        scb[(long)rr * 256 + ((10 + j) * 16 + dl - 64)] = f2bf(acc[j][r]);
                }
            }
        }
#pragma unroll
        for (int j = 0; j < 10; j++) {
            float s = 0.f, q = 0.f;
#pragma unroll
            for (int r = 0; r < 4; r++) {
                float v = ((m0 + rb + r) < M) ? acc[j][r] : 0.f;
                s += v; q += v * v;
            }
            s += __shfl_xor(s, 16); s += __shfl_xor(s, 32);
            q += __shfl_xor(q, 16); q += __shfl_xor(q, 32);
            if (q4 == 0) {
                atomicAdd(&sred[(half * 10 + j) * 16 + dl], s);
                atomicAdd(&qred[(half * 10 + j) * 16 + dl], q);
            }
        }
    }
    __syncthreads();
    for (int c = t; c < 320; c += 256) {
        if (c < 64) { atomicAdd(&Sa1[c], sred[c]); atomicAdd(&Sq1[c], qred[c]); }
        else        { atomicAdd(&SaS[c - 64], sred[c]); atomicAdd(&SqS[c - 64], qred[c]); }
    }
}

// ---------- BN1 + lrelu on permuted x1 (channel = d(m)) ----------
__global__ __launch_bounds__(256)
void k_bnx(const ushort* __restrict__ X, ushort* __restrict__ Y,
           const float* __restrict__ Sa, const float* __restrict__ Sq,
           const float* __restrict__ g, const float* __restrict__ b) {
    __shared__ float sc[64], sh[64];
    int t = threadIdx.x;
    if (t < 64) {
        float m = Sa[t] * INVN;
        float v = Sq[t] * INVN - m * m;
        float s = g[t] * rsqrtf(v + EPSV);
        sc[t] = s; sh[t] = b[t] - s * m;
    }
    __syncthreads();
    int i = blockIdx.x * 256 + t;
    long base = (long)i * 4;
    int dlp = i & 15;           // m0 = 4*dlp; element j has channel j*16+dlp
    ull vin = *(const ull*)(X + base);
    ull vout = 0;
#pragma unroll
    for (int j = 0; j < 4; j++) {
        int c = j * 16 + dlp;
        float f = bf2f((ushort)((vin >> (16 * j)) & 0xffff));
        float v = f * sc[c] + sh[c];
        v = (v >= 0.f) ? v : SLOPE * v;
        vout |= ((ull)f2bf(v)) << (16 * j);
    }
    *(ull*)(Y + base) = vout;
}

// ---------- fused KPConv: b64 gather on permuted x1, all-MFMA ----------
__global__ __launch_bounds__(256)
void k_kpconv(const float* __restrict__ qpts, const float* __restrict__ spts,
              const int* __restrict__ nbr, const ushort* __restrict__ x1b,
              const float* __restrict__ kpp, const ushort* __restrict__ kwp,
              ushort* __restrict__ y, float* __restrict__ Sa, float* __restrict__ Sq) {
    __shared__ __align__(16) ushort wfs[16][1032];  // [p][kd], kd=d*16+k, pitch 1032
    __shared__ float posd[4][3][HN];
    __shared__ int   sidx[4][HN];

    int t = threadIdx.x;
    int w = t >> 6, l = t & 63;
    int dl = l & 15, q4 = l >> 4;

    int kmin = (dl < KP) ? dl : (KP - 1);
    float kx = kpp[kmin * 3 + 0], ky = kpp[kmin * 3 + 1], kz = kpp[kmin * 3 + 2];

    for (int pp = 0; pp < 4; pp++) {
        int p = w * 4 + pp;
        int n = blockIdx.x * 16 + p;

        // neighbor indices + deltas (lanes 0..31); wave-synchronous
        if (l < HN) {
            int idx = nbr[n * HN + l];
            sidx[w][l] = idx;
            float qx = qpts[n * 3 + 0], qy = qpts[n * 3 + 1], qz = qpts[n * 3 + 2];
            posd[w][0][l] = spts[idx * 3 + 0] - qx;
            posd[w][1][l] = spts[idx * 3 + 1] - qy;
            posd[w][2][l] = spts[idx * 3 + 2] - qz;
        }

        // gather 8 rows x one b64 each (permuted layout -> 4 B-frag elems/load)
        uint2 rj[8];
#pragma unroll
        for (int j = 0; j < 8; j++) {
            const ull* pj = (const ull*)(x1b + (long)sidx[w][q4 * 8 + j] * MIDF + 4 * dl);
            union { ull u; uint2 d; } tmp; tmp.u = *pj;
            rj[j] = tmp.d;
        }

        // A-frag: influences, lane owns A[m=dl(kp)][k=h=q4*8+j]
        union { short8 v; ushort u8[8]; } afr;
#pragma unroll
        for (int j = 0; j < 8; j++) {
            int h = q4 * 8 + j;
            float ex = posd[w][0][h] - kx;
            float ey = posd[w][1][h] - ky;
            float ez = posd[w][2][h] - kz;
            float sq = ex * ex + ey * ey + ez * ez;
            float dist = sqrtf(fmaxf(sq, 1e-12f));
            float inf = fmaxf(0.f, 1.f - dist * (1.f / KPE));
            afr.u8[j] = (dl < KP) ? f2bf(inf) : (ushort)0;
        }

        // transpose 8 x (4 u16) -> 4 B-frags of 8 u16 via v_perm
        union { short8 v; unsigned d[4]; } bfr[4];
#pragma unroll
        for (int dj = 0; dj < 4; dj++) {
            unsigned a_lo = rj[2 * dj].x, b_lo = rj[2 * dj + 1].x;
            unsigned a_hi = rj[2 * dj].y, b_hi = rj[2 * dj + 1].y;
            bfr[0].d[dj] = __builtin_amdgcn_perm(b_lo, a_lo, 0x05040100u);
            bfr[1].d[dj] = __builtin_amdgcn_perm(b_lo, a_lo, 0x07060302u);
            bfr[2].d[dj] = __builtin_amdgcn_perm(b_hi, a_hi, 0x05040100u);
            bfr[3].d[dj] = __builtin_amdgcn_perm(b_hi, a_hi, 0x07060302u);
        }

        float4v wfa[4];
#pragma unroll
        for (int nt = 0; nt < 4; nt++)
            wfa[nt] = __builtin_amdgcn_mfma_f32_16x16x32_bf16(
                afr.v, bfr[nt].v, (float4v){0.f, 0.f, 0.f, 0.f}, 0, 0, 0);

        // wf write: wfs[p][d*16+k], d=nt*16+dl, k=q4*4+r (k>=15 -> 0); packed b64
#pragma unroll
        for (int nt = 0; nt < 4; nt++) {
            ull pk = 0;
#pragma unroll
            for (int r = 0; r < 4; r++) {
                ushort hv = ((q4 * 4 + r) < KP) ? f2bf(wfa[nt][r]) : (ushort)0;
                pk |= ((ull)hv) << (16 * r);
            }
            *(ull*)(&wfs[p][(nt * 16 + dl) * 16 + q4 * 4]) = pk;
        }
    }
    __syncthreads();

    // phase 3: y[16][64] = wf[16][1024] @ wpk[1024][64]; wave w -> col tile w
    float4v acc = (float4v){0.f, 0.f, 0.f, 0.f};
    const ushort* arow = &wfs[dl][0] + q4 * 8;
    const short8* Bp = (const short8*)kwp + l;
#pragma unroll 8
    for (int s = 0; s < 32; s++) {
        short8 af = *(const short8*)(arow + s * 32);
        short8 bf = Bp[(s * 4 + w) * 64];
        acc = __builtin_amdgcn_mfma_f32_16x16x32_bf16(af, bf, acc, 0, 0, 0);
    }

    int o = w * 16 + dl;
    float s = 0.f, q = 0.f;
#pragma unroll
    for (int r = 0; r < 4; r++) {
        float v = acc[r];
        y[(long)(blockIdx.x * 16 + q4 * 4 + r) * MIDF + o] = f2bf(v);
        s += v; q += v * v;
    }
    s += __shfl_xor(s, 16); s += __shfl_xor(s, 32);
    q += __shfl_xor(q, 16); q += __shfl_xor(q, 32);
    if (q4 == 0) {
        atomicAdd(&Sa[o], s);
        atomicAdd(&Sq[o], q);
    }
}

// ---------- conv3 GEMM (BN2 inline on A), fused stats, bf16 out ----------
__global__ __launch_bounds__(256)
void k_conv3(const ushort* __restrict__ x2raw, const ushort* __restrict__ Wp,
             ushort* __restrict__ x3b,
             const float* __restrict__ Sa2, const float* __restrict__ Sq2,
             const float* __restrict__ g2, const float* __restrict__ b2,
             float* __restrict__ Sa3, float* __restrict__ Sq3, int M) {
    __shared__ float sred[256], qred[256];
    __shared__ float scs[64], shs[64];
    int t = threadIdx.x;
    int w = t >> 6, l = t & 63;
    int dl = l & 15, q4 = l >> 4;

    if (t < 64) {
        float m = Sa2[t] * INVN;
        float v = Sq2[t] * INVN - m * m;
        float s = g2[t] * rsqrtf(v + EPSV);
        scs[t] = s; shs[t] = b2[t] - s * m;
    }
    sred[t] = 0.f; qred[t] = 0.f;
    __syncthreads();

    int m0 = blockIdx.x * 64 + w * 16;
    int row = m0 + dl;
    long arow = (row < M) ? row : (M - 1);
    const ushort* ap0 = x2raw + arow * MIDF + q4 * 8;
    short8 au2[2];
#pragma unroll
    for (int s = 0; s < 2; s++) {
        union { short8 v; ushort u[8]; } raw, cv;
        raw.v = *(const short8*)(ap0 + s * 32);
#pragma unroll
        for (int e = 0; e < 8; e++) {
            int d = s * 32 + q4 * 8 + e;
            float f = bf2f(raw.u[e]) * scs[d] + shs[d];
            f = (f >= 0.f) ? f : SLOPE * f;
            cv.u[e] = f2bf(f);
        }
        au2[s] = cv.v;
    }
    const short8* Bp = (const short8*)Wp + l;
    int rb = q4 * 4;
#pragma unroll
    for (int half = 0; half < 2; half++) {
        float4v acc[8];
#pragma unroll
        for (int j = 0; j < 8; j++) acc[j] = (float4v){0.f, 0.f, 0.f, 0.f};
#pragma unroll
        for (int s = 0; s < 2; s++)
#pragma unroll
            for (int j = 0; j < 8; j++) {
                short8 bf = Bp[(s * 16 + half * 8 + j) * 64];
                acc[j] = __builtin_amdgcn_mfma_f32_16x16x32_bf16(au2[s], bf, acc[j], 0, 0, 0);
            }
#pragma unroll
        for (int r = 0; r < 4; r++) {
            int rr = m0 + rb + r;
            if (rr < M) {
#pragma unroll
                for (int j = 0; j < 8; j++)
                    x3b[(long)rr * 256 + (half * 8 + j) * 16 + dl] = f2bf(acc[j][r]);
            }
        }
#pragma unroll
        for (int j = 0; j < 8; j++) {
            float s = 0.f, q = 0.f;
#pragma unroll
            for (int r = 0; r < 4; r++) {
                float v = ((m0 + rb + r) < M) ? acc[j][r] : 0.f;
                s += v; q += v * v;
            }
            s += __shfl_xor(s, 16); s += __shfl_xor(s, 32);
            q += __shfl_xor(q, 16); q += __shfl_xor(q, 32);
            if (q4 == 0) {
                atomicAdd(&sred[(half * 8 + j) * 16 + dl], s);
                atomicAdd(&qred[(half * 8 + j) * 16 + dl], q);
            }
        }
    }
    __syncthreads();
    atomicAdd(&Sa3[t], sred[t]);
    atomicAdd(&Sq3[t], qred[t]);
}

// ---------- final: inline finstats, lrelu(lrelu_bn(x3b) + lrelu_bn(scb)) -> f32 ----------
__global__ __launch_bounds__(256)
void k_final(const ushort* __restrict__ x3b, const ushort* __restrict__ scb,
             float* __restrict__ out,
             const float* __restrict__ a3, const float* __restrict__ q3,
             const float* __restrict__ g3, const float* __restrict__ b3,
             const float* __restrict__ aS, const float* __restrict__ qS,
             const float* __restrict__ gs, const float* __restrict__ bs) {
    __shared__ float s3[256], h3[256], sS[256], hS[256];
    int t = threadIdx.x;
    {
        float m = a3[t] * INVN;
        float v = q3[t] * INVN - m * m;
        float s = g3[t] * rsqrtf(v + EPSV);
        s3[t] = s; h3[t] = b3[t] - s * m;
        m = aS[t] * INVN;
        v = qS[t] * INVN - m * m;
        s = gs[t] * rsqrtf(v + EPSV);
        sS[t] = s; hS[t] = bs[t] - s * m;
    }
    __syncthreads();
    long i = (long)(blockIdx.x * 256 + t) * 4;
    int c0 = (int)(i & 255);
    ull va = *(const ull*)(x3b + i);
    ull vb = *(const ull*)(scb + i);
    float r[4];
#pragma unroll
    for (int j = 0; j < 4; j++) {
        int c = c0 + j;
        float x = bf2f((ushort)((va >> (16 * j)) & 0xffff)) * s3[c] + h3[c];
        x = (x >= 0.f) ? x : SLOPE * x;
        float sc = bf2f((ushort)((vb >> (16 * j)) & 0xffff)) * sS[c] + hS[c];
        sc = (sc >= 0.f) ? sc : SLOPE * sc;
        float v = x + sc;
        r[j] = (v >= 0.f) ? v : SLOPE * v;
    }
    *(float4*)(out + i) = (float4){r[0], r[1], r[2], r[3]};
}

extern "C" void kernel_launch(void* const* d_in, const int* in_sizes, int n_in,
                              void* d_out, int out_size, void* d_ws, size_t ws_size,
                              hipStream_t stream) {
    const float* qp   = (const float*)d_in[0];
    const float* sp   = (const float*)d_in[1];
    const int*   nbr  = (const int*)d_in[2];
    const float* feat = (const float*)d_in[3];
    const float* kpp  = (const float*)d_in[4];
    const float* w1   = (const float*)d_in[5];
    const float* g1   = (const float*)d_in[6];
    const float* b1   = (const float*)d_in[7];
    const float* kw   = (const float*)d_in[8];
    const float* g2   = (const float*)d_in[9];
    const float* b2   = (const float*)d_in[10];
    const float* w3   = (const float*)d_in[11];
    const float* g3   = (const float*)d_in[12];
    const float* b3   = (const float*)d_in[13];
    const float* wsw  = (const float*)d_in[14];
    const float* gs   = (const float*)d_in[15];
    const float* bs   = (const float*)d_in[16];
    float* out = (float*)d_out;

    char* base = (char*)d_ws;
    ushort* x1raw = (ushort*)(base + 0);          // 6.4 MB (permuted layout)
    ushort* x1b   = (ushort*)(base + 6400000);    // 6.4 MB (permuted layout)
    ushort* x2raw = (ushort*)(base + 12800000);   // 6.4 MB
    ushort* x3b   = (ushort*)(base + 19200000);   // 25.6 MB
    ushort* scb   = (ushort*)(base + 44800000);   // 25.6 MB
    ushort* wpC   = (ushort*)(base + 70400000);   // 80 KB
    ushort* wpk   = (ushort*)(base + 70481920);   // 128 KB (K=1024)
    ushort* wp3   = (ushort*)(base + 70612992);   // 32 KB
    float*  st    = (float*)(base + 70645760);
    float* acc1 = st,       *q1 = st + 64;
    float* acc2 = st + 128, *q2 = st + 192;
    float* acc3 = st + 256, *q3 = st + 512;
    float* accS = st + 768, *qS = st + 1024;

    hipMemsetAsync(st, 0, 1280 * sizeof(float), stream);

    k_repack_all<<<60, 256, 0, stream>>>(w1, wsw, wpC, kw, wpk, w3, wp3);

    // conv1 + shortcut fused (feat read once); x1 written permuted+packed
    k_conv1sc<<<782, 256, 0, stream>>>(feat, wpC, x1raw, scb, acc1, q1, accS, qS, NPTS);
    k_bnx<<<3125, 256, 0, stream>>>(x1raw, x1b, acc1, q1, g1, b1);

    // KPConv: b64 gather on permuted x1 + MFMA, fused stats
    k_kpconv<<<NPTS / 16, 256, 0, stream>>>(qp, sp, nbr, x1b, kpp, wpk, x2raw, acc2, q2);

    // conv3 with inline BN2+lrelu on A, fused stats, bf16 out
    k_conv3<<<782, 256, 0, stream>>>(x2raw, wp3, x3b, acc2, q2, g2, b2, acc3, q3, NPTS);

    // final combine (inline finstats for both BNs)
    k_final<<<12500, 256, 0, stream>>>(x3b, scb, out, acc3, q3, g3, b3, accS, qS, gs, bs);
}